// Round 2
// baseline (984.696 us; speedup 1.0000x reference)
//
#include <hip/hip_runtime.h>
#include <stdint.h>

#define S_LEN 2048
#define HD 4096            // H*D row stride in floats
#define QB 32
#define KB 32

#define LAMBDA_INIT_F 0.78360576654f
#define ONE_MINUS_LI  0.21639423346f
#define SCALE_F 0.08838834764831845f  // 1/sqrt(128)

typedef __attribute__((ext_vector_type(8))) short bf16x8;
typedef __attribute__((ext_vector_type(4))) float f32x4;
typedef __attribute__((ext_vector_type(4))) uint32_t u32x4;
typedef __attribute__((ext_vector_type(2))) uint32_t u32x2;

// LDS layout (bytes): Q[2][32][128]bf16 @0 (16KB), K @16384 (16KB),
// Vt[256][32]bf16 @32768 (16KB), P[2][32][40]bf16 @49152 (5KB).
// Epilogue overlay: X2[32][260] f32 @0 (33280B), Ssum[2][64] f32 @33280.
#define SMB_K 16384u
#define SMB_V 32768u
#define SMB_P 49152u
#define SMB_SS 33280u
#define SM_SHORTS 27136

__device__ __forceinline__ unsigned short f2bf(float x) {
  union { float f; uint32_t u; } v; v.f = x;
  uint32_t u = v.u;
  u += 0x7FFFu + ((u >> 16) & 1u);
  return (unsigned short)(u >> 16);
}
__device__ __forceinline__ uint32_t pack2bf(float a, float b) {
  return (uint32_t)f2bf(a) | ((uint32_t)f2bf(b) << 16);
}
// Q/K tiles: [att][row 0..31][d 0..127] bf16, row stride 256B, XOR-swizzled (G4 fix)
__device__ __forceinline__ uint32_t qk_byte(int att, int row, int d) {
  uint32_t b0 = (((uint32_t)(att * 32 + row)) << 8) + ((uint32_t)d << 1);
  return b0 ^ (((uint32_t)(row & 7)) << 4);
}
// V transposed: [col 0..255][k 0..31] bf16, row stride 64B, XOR-swizzled
__device__ __forceinline__ uint32_t v_byte(int col, int kk) {
  uint32_t b0 = ((uint32_t)col << 6) + ((uint32_t)kk << 1);
  return b0 ^ ((((uint32_t)((col >> 1) ^ (col >> 3))) & 3u) << 4);
}
// P: [att][q 0..31][k 0..39(pad)] bf16
__device__ __forceinline__ uint32_t p_byte(int att, int qrow, int kcol) {
  return SMB_P + ((uint32_t)((att * 32 + qrow) * 40 + kcol) << 1);
}

__global__ __launch_bounds__(256, 3)
void diffattn_fwd(const float* __restrict__ Qg, const float* __restrict__ Kg,
                  const float* __restrict__ Vg,
                  const float* __restrict__ lq1, const float* __restrict__ lk1,
                  const float* __restrict__ lq2, const float* __restrict__ lk2,
                  const float* __restrict__ Wg, float* __restrict__ Og) {
  __shared__ __align__(16) unsigned short smem[SM_SHORTS];
  char* sm = (char*)smem;

  const int tid = threadIdx.x;
  const int lane = tid & 63;
  const int c = lane & 15;       // MFMA col / A-row lane index
  const int g = lane >> 4;       // MFMA k-group
  const int wv = tid >> 6;
  const int att = wv >> 1;       // 0: q1/k1 attn, 1: q2/k2 attn
  const int ch = wv & 1;         // V col half

  // block swizzle: 4 (b,hp) per XCD, qt descending (heavy blocks first)
  const int n = blockIdx.x;
  const int bh = (n & 7) * 4 + ((n >> 3) >> 6);
  const int qt = 63 - ((n >> 3) & 63);
  const int b = bh >> 4;
  const int hp = bh & 15;
  const int qb = qt * QB;

  const size_t base = (size_t)b * S_LEN * HD + (size_t)hp * 256;
  const float* qg = Qg + base + (size_t)qb * HD;
  const float* kgp = Kg + base;
  const float* vgp = Vg + base;

  // lambda = exp(lq1.lk1) - exp(lq2.lk2) + lambda_init  (per-wave shuffle reduce)
  float d1 = lq1[lane] * lk1[lane] + lq1[lane + 64] * lk1[lane + 64];
  float d2 = lq2[lane] * lk2[lane] + lq2[lane + 64] * lk2[lane + 64];
  #pragma unroll
  for (int m = 1; m < 64; m <<= 1) {
    d1 += __shfl_xor(d1, m, 64);
    d2 += __shfl_xor(d2, m, 64);
  }
  const float lam = __expf(d1) - __expf(d2) + LAMBDA_INIT_F;

  // stage Q (scale folded into bf16 convert)
  #pragma unroll
  for (int j = 0; j < 8; ++j) {
    int idx = tid + 256 * j;
    int r = idx >> 6;
    int c4 = idx & 63;
    const float4 f = *(const float4*)(qg + (size_t)r * HD + c4 * 4);
    u32x2 hv;
    hv.x = pack2bf(f.x * SCALE_F, f.y * SCALE_F);
    hv.y = pack2bf(f.z * SCALE_F, f.w * SCALE_F);
    *(u32x2*)(sm + qk_byte(c4 >> 5, r, (c4 & 31) * 4)) = hv;
  }
  __syncthreads();

  // Q fragments resident in registers: Q[16*qi + c][32*kk + 8g .. +7]
  bf16x8 qf[2][4];
  #pragma unroll
  for (int qi = 0; qi < 2; ++qi)
    #pragma unroll
    for (int kk = 0; kk < 4; ++kk)
      qf[qi][kk] = *(const bf16x8*)(sm + qk_byte(att, 16 * qi + c, 32 * kk + 8 * g));

  f32x4 o[2][8];
  #pragma unroll
  for (int qi = 0; qi < 2; ++qi)
    #pragma unroll
    for (int cf = 0; cf < 8; ++cf)
      o[qi][cf] = (f32x4){0.f, 0.f, 0.f, 0.f};
  float mrow[2] = {-1e30f, -1e30f};
  float lrow[2] = {0.f, 0.f};

  for (int kt = 0; kt <= qt; ++kt) {
    __syncthreads();  // previous iteration's LDS consumers done
    // ---- stage K12 (row-major swizzled) ----
    const float* kt_p = kgp + (size_t)(kt * KB) * HD;
    #pragma unroll
    for (int j = 0; j < 8; ++j) {
      int idx = tid + 256 * j;
      int r = idx >> 6;
      int c4 = idx & 63;
      const float4 f = *(const float4*)(kt_p + (size_t)r * HD + c4 * 4);
      u32x2 hv;
      hv.x = pack2bf(f.x, f.y);
      hv.y = pack2bf(f.z, f.w);
      *(u32x2*)(sm + SMB_K + qk_byte(c4 >> 5, r, (c4 & 31) * 4)) = hv;
    }
    // ---- stage V12 transposed: thread owns 4 cols x 8 k ----
    {
      const float* vt_p = vgp + (size_t)(kt * KB) * HD;
      const int c4 = tid & 63;
      const int kg8 = tid >> 6;
      #pragma unroll
      for (int hh = 0; hh < 2; ++hh) {
        float4 f0 = *(const float4*)(vt_p + (size_t)(8 * kg8 + 4 * hh + 0) * HD + c4 * 4);
        float4 f1 = *(const float4*)(vt_p + (size_t)(8 * kg8 + 4 * hh + 1) * HD + c4 * 4);
        float4 f2 = *(const float4*)(vt_p + (size_t)(8 * kg8 + 4 * hh + 2) * HD + c4 * 4);
        float4 f3 = *(const float4*)(vt_p + (size_t)(8 * kg8 + 4 * hh + 3) * HD + c4 * 4);
        #pragma unroll
        for (int dd = 0; dd < 4; ++dd) {
          u32x2 pk;
          pk.x = pack2bf((&f0.x)[dd], (&f1.x)[dd]);
          pk.y = pack2bf((&f2.x)[dd], (&f3.x)[dd]);
          *(u32x2*)(sm + SMB_V + v_byte(4 * c4 + dd, 8 * kg8 + 4 * hh)) = pk;
        }
      }
    }
    __syncthreads();

    // ---- S^T = K * Q^T  (swapped so k-rows live in C/D rows, q in lanes) ----
    f32x4 st[2][2];
    #pragma unroll
    for (int ki = 0; ki < 2; ++ki)
      #pragma unroll
      for (int qi = 0; qi < 2; ++qi)
        st[ki][qi] = (f32x4){0.f, 0.f, 0.f, 0.f};
    #pragma unroll
    for (int kk = 0; kk < 4; ++kk) {
      bf16x8 kf0 = *(const bf16x8*)(sm + SMB_K + qk_byte(att, c, 32 * kk + 8 * g));
      bf16x8 kf1 = *(const bf16x8*)(sm + SMB_K + qk_byte(att, 16 + c, 32 * kk + 8 * g));
      st[0][0] = __builtin_amdgcn_mfma_f32_16x16x32_bf16(kf0, qf[0][kk], st[0][0], 0, 0, 0);
      st[0][1] = __builtin_amdgcn_mfma_f32_16x16x32_bf16(kf0, qf[1][kk], st[0][1], 0, 0, 0);
      st[1][0] = __builtin_amdgcn_mfma_f32_16x16x32_bf16(kf1, qf[0][kk], st[1][0], 0, 0, 0);
      st[1][1] = __builtin_amdgcn_mfma_f32_16x16x32_bf16(kf1, qf[1][kk], st[1][1], 0, 0, 0);
    }
    // causal mask on diagonal tile: S^T[krow][qcol], mask krow > qcol
    if (kt == qt) {
      #pragma unroll
      for (int ki = 0; ki < 2; ++ki)
        #pragma unroll
        for (int qi = 0; qi < 2; ++qi)
          #pragma unroll
          for (int r = 0; r < 4; ++r)
            if (16 * ki + 4 * g + r > 16 * qi + c) st[ki][qi][r] = -1e30f;
    }
    // ---- online softmax (row = q = 16qi + c, reduce over k: in-lane + g-groups) ----
    #pragma unroll
    for (int qi = 0; qi < 2; ++qi) {
      float mx = st[0][qi][0];
      #pragma unroll
      for (int r = 1; r < 4; ++r) mx = fmaxf(mx, st[0][qi][r]);
      #pragma unroll
      for (int r = 0; r < 4; ++r) mx = fmaxf(mx, st[1][qi][r]);
      mx = fmaxf(mx, __shfl_xor(mx, 16, 64));
      mx = fmaxf(mx, __shfl_xor(mx, 32, 64));
      float mnew = fmaxf(mrow[qi], mx);
      float alpha = __expf(mrow[qi] - mnew);
      mrow[qi] = mnew;
      float p[2][4];
      float sum = 0.f;
      #pragma unroll
      for (int ki = 0; ki < 2; ++ki)
        #pragma unroll
        for (int r = 0; r < 4; ++r) {
          p[ki][r] = __expf(st[ki][qi][r] - mnew);
          sum += p[ki][r];
        }
      sum += __shfl_xor(sum, 16, 64);
      sum += __shfl_xor(sum, 32, 64);
      lrow[qi] = lrow[qi] * alpha + sum;
      // write P[q][k] (pair waves write identical values -> benign, no barrier)
      #pragma unroll
      for (int ki = 0; ki < 2; ++ki)
        #pragma unroll
        for (int rp = 0; rp < 2; ++rp) {
          uint32_t pw = pack2bf(p[ki][2 * rp], p[ki][2 * rp + 1]);
          *(uint32_t*)(sm + p_byte(att, 16 * qi + c, 16 * ki + 4 * g + 2 * rp)) = pw;
        }
      // rescale O by alpha of its rows (rows = 4g + r)
      float av[4];
      #pragma unroll
      for (int r = 0; r < 4; ++r) av[r] = __shfl(alpha, 4 * g + r, 64);
      #pragma unroll
      for (int cf = 0; cf < 8; ++cf)
        #pragma unroll
        for (int r = 0; r < 4; ++r) o[qi][cf][r] *= av[r];
    }
    // ---- PV: O[q][col] += P[q][k] * V[k][col] ----
    bf16x8 pa0 = *(const bf16x8*)(sm + p_byte(att, c, 8 * g));
    bf16x8 pa1 = *(const bf16x8*)(sm + p_byte(att, 16 + c, 8 * g));
    #pragma unroll
    for (int cf = 0; cf < 8; ++cf) {
      bf16x8 vf = *(const bf16x8*)(sm + SMB_V + v_byte(128 * ch + 16 * cf + c, 8 * g));
      o[0][cf] = __builtin_amdgcn_mfma_f32_16x16x32_bf16(pa0, vf, o[0][cf], 0, 0, 0);
      o[1][cf] = __builtin_amdgcn_mfma_f32_16x16x32_bf16(pa1, vf, o[1][cf], 0, 0, 0);
    }
  }

  // ---- epilogue (all fp32): attn2 waves export via LDS, attn1 waves combine ----
  __syncthreads();  // all waves done with staged tiles before overlay
  float lv[2][4];
  {
    float linv0 = 1.f / lrow[0];
    float linv1 = 1.f / lrow[1];
    #pragma unroll
    for (int r = 0; r < 4; ++r) {
      lv[0][r] = __shfl(linv0, 4 * g + r, 64);
      lv[1][r] = __shfl(linv1, 4 * g + r, 64);
    }
  }
  float* X2 = (float*)sm;                 // [32][260] f32
  float* Ssum = (float*)(sm + SMB_SS);    // [2][64] f32

  if (att == 1) {
    #pragma unroll
    for (int qi = 0; qi < 2; ++qi)
      #pragma unroll
      for (int cf = 0; cf < 8; ++cf)
        #pragma unroll
        for (int r = 0; r < 4; ++r)
          X2[(16 * qi + 4 * g + r) * 260 + 128 * ch + 16 * cf + c] =
              o[qi][cf][r] * lv[qi][r];
  }
  __syncthreads();
  if (att == 0) {
    float ss[2][4] = {{0.f, 0.f, 0.f, 0.f}, {0.f, 0.f, 0.f, 0.f}};
    #pragma unroll
    for (int qi = 0; qi < 2; ++qi)
      #pragma unroll
      for (int cf = 0; cf < 8; ++cf)
        #pragma unroll
        for (int r = 0; r < 4; ++r) {
          float xx = o[qi][cf][r] * lv[qi][r] -
                     lam * X2[(16 * qi + 4 * g + r) * 260 + 128 * ch + 16 * cf + c];
          o[qi][cf][r] = xx;
          ss[qi][r] += xx * xx;
        }
    #pragma unroll
    for (int m = 1; m < 16; m <<= 1)
      #pragma unroll
      for (int qi = 0; qi < 2; ++qi)
        #pragma unroll
        for (int r = 0; r < 4; ++r)
          ss[qi][r] += __shfl_xor(ss[qi][r], m, 64);
    if (c == 0) {
      #pragma unroll
      for (int qi = 0; qi < 2; ++qi)
        #pragma unroll
        for (int r = 0; r < 4; ++r)
          Ssum[ch * 64 + 16 * qi + 4 * g + r] = ss[qi][r];
    }
  }
  __syncthreads();
  if (att == 0) {
    float rsv[2][4];
    #pragma unroll
    for (int qi = 0; qi < 2; ++qi)
      #pragma unroll
      for (int r = 0; r < 4; ++r) {
        int row = 16 * qi + 4 * g + r;
        float s = Ssum[row] + Ssum[64 + row];
        rsv[qi][r] = rsqrtf(s * (1.f / 256.f) + 1e-5f) * ONE_MINUS_LI;
      }
    #pragma unroll
    for (int cf = 0; cf < 8; ++cf) {
      float w = Wg[128 * ch + 16 * cf + c];
      #pragma unroll
      for (int qi = 0; qi < 2; ++qi)
        #pragma unroll
        for (int r = 0; r < 4; ++r) {
          int row = 16 * qi + 4 * g + r;
          Og[(size_t)((size_t)b * S_LEN + qb + row) * HD + hp * 256 +
             128 * ch + 16 * cf + c] = w * o[qi][cf][r] * rsv[qi][r];
        }
    }
  }
}

extern "C" void kernel_launch(void* const* d_in, const int* in_sizes, int n_in,
                              void* d_out, int out_size, void* d_ws, size_t ws_size,
                              hipStream_t stream) {
  const float* q   = (const float*)d_in[0];
  const float* k   = (const float*)d_in[1];
  const float* v   = (const float*)d_in[2];
  const float* lq1 = (const float*)d_in[3];
  const float* lk1 = (const float*)d_in[4];
  const float* lq2 = (const float*)d_in[5];
  const float* lk2 = (const float*)d_in[6];
  const float* w   = (const float*)d_in[7];
  float* out = (float*)d_out;
  hipLaunchKernelGGL(diffattn_fwd, dim3(2048), dim3(256), 0, stream,
                     q, k, v, lq1, lk1, lq2, lk2, w, out);
}